// Round 1
// baseline (144.361 us; speedup 1.0000x reference)
//
#include <hip/hip_runtime.h>

// ---------------- types & helpers ----------------
using short8 = __attribute__((ext_vector_type(8))) short;   // 8 x bf16 (4 VGPRs)
using f32x4  = __attribute__((ext_vector_type(4))) float;
using u16x4  = __attribute__((ext_vector_type(4))) unsigned short;

#define MFMA16(A,B,C) __builtin_amdgcn_mfma_f32_16x16x32_bf16((A),(B),(C),0,0,0)

__device__ __forceinline__ unsigned short f2b(float f) {
  unsigned u = __float_as_uint(f);
  return (unsigned short)((u + 0x7fffu + ((u >> 16) & 1u)) >> 16);  // RNE
}

// 8 consecutive f32 -> bf16x8 fragment
__device__ __forceinline__ short8 w8(const float* p) {
  const f32x4* q = (const f32x4*)p;
  f32x4 a = q[0], b = q[1];
  short8 r;
  r[0]=(short)f2b(a[0]); r[1]=(short)f2b(a[1]); r[2]=(short)f2b(a[2]); r[3]=(short)f2b(a[3]);
  r[4]=(short)f2b(b[0]); r[5]=(short)f2b(b[1]); r[6]=(short)f2b(b[2]); r[7]=(short)f2b(b[3]);
  return r;
}

// T=512, N=128, D=64, H=4, HID=OUT=64

// ---------------- kernel 1: xin = x + pe, transpose to [N][T][D] bf16 ----------------
__global__ void prep_kernel(const float* __restrict__ x, const float* __restrict__ pe,
                            unsigned* __restrict__ xinT) {
  int i2 = blockIdx.x * 256 + threadIdx.x;      // handles elements 2*i2, 2*i2+1
  const float2* xp = (const float2*)x;
  const float2* pp = (const float2*)pe;
  float2 a = xp[i2], b = pp[i2];
  float s0 = a.x + b.x, s1 = a.y + b.y;
  int i   = i2 << 1;
  int t   = i >> 13;          // / (N*D=8192)
  int rem = i & 8191;
  int n   = rem >> 6;
  int d   = rem & 63;
  unsigned v = (unsigned)f2b(s0) | ((unsigned)f2b(s1) << 16);
  xinT[((n * 512 + t) * 64 + d) >> 1] = v;
}

// ---------------- kernel 2: per-(h,n) fused QKV-proj + causal flash attention ----------------
__global__ __launch_bounds__(256) void attn_kernel(
    const unsigned short* __restrict__ xinT,
    const float* __restrict__ wq, const float* __restrict__ wk,
    const float* __restrict__ wv, unsigned short* __restrict__ heads) {
  // LDS: K row-major [s][e], V transposed [o][s], per-wave 32x64 scratch. All XOR-swizzled.
  __shared__ unsigned short sK[512 * 64];       // 64 KB
  __shared__ unsigned short sVT[64 * 512];      // 64 KB
  __shared__ unsigned short sQ[4][32 * 64];     // 16 KB

  const int h  = blockIdx.x & 3;
  const int n  = blockIdx.x >> 2;
  const int w  = threadIdx.x >> 6;
  const int l  = threadIdx.x & 63;
  const int lg = l >> 4;      // lane group 0..3
  const int lm = l & 15;      // lane mod 16

  const unsigned short* xn = xinT + n * (512 * 64);
  const f32x4 zero4 = {0.f, 0.f, 0.f, 0.f};

  // ---- wk, wv B-fragments (e = lane%16 col, d = kappa1(g,i)=ks*32+8g+i) ----
  short8 wkB[4][2], wvB[4][2];
  {
    const float* bk = wk + h * 64 * 64;
    const float* bv = wv + h * 64 * 64;
#pragma unroll
    for (int nt = 0; nt < 4; ++nt)
#pragma unroll
      for (int ks = 0; ks < 2; ++ks) {
        int off = (nt * 16 + lm) * 64 + ks * 32 + lg * 8;
        wkB[nt][ks] = w8(bk + off);
        wvB[nt][ks] = w8(bv + off);
      }
  }

  // ---- stage K and V^T into LDS (wave w owns source rows [128w,128w+128)) ----
  for (int mt = 0; mt < 8; ++mt) {
    int s0 = w * 128 + mt * 16;
    short8 aX[2];
#pragma unroll
    for (int ks = 0; ks < 2; ++ks)
      aX[ks] = *(const short8*)(xn + (s0 + lm) * 64 + ks * 32 + lg * 8);
#pragma unroll
    for (int nt = 0; nt < 4; ++nt) {
      f32x4 aK = zero4, aV = zero4;
      aK = MFMA16(aX[0], wkB[nt][0], aK);
      aK = MFMA16(aX[1], wkB[nt][1], aK);
      aV = MFMA16(aX[0], wvB[nt][0], aV);
      aV = MFMA16(aX[1], wvB[nt][1], aV);
      // K[s][e]; C layout: row = s0+4*lg+r, col e = nt*16+lm
#pragma unroll
      for (int r = 0; r < 4; ++r) {
        int row = s0 + lg * 4 + r;
        int e   = nt * 16 + lm;
        sK[row * 64 + (e ^ ((row & 7) << 3))] = f2b(aK[r]);
      }
      // V^T[o][s]: o = nt*16+lm, s = s0+4*lg..+3 (contiguous -> 8B write)
      {
        int o  = nt * 16 + lm;
        int sb = s0 + lg * 4;
        u16x4 v;
        v[0]=f2b(aV[0]); v[1]=f2b(aV[1]); v[2]=f2b(aV[2]); v[3]=f2b(aV[3]);
        *(u16x4*)&sVT[o * 512 + (sb ^ ((o & 7) << 3))] = v;
      }
    }
  }

  // ---- wq B-fragments ----
  short8 wqB[4][2];
  {
    const float* bq = wq + h * 64 * 64;
#pragma unroll
    for (int nt = 0; nt < 4; ++nt)
#pragma unroll
      for (int ks = 0; ks < 2; ++ks)
        wqB[nt][ks] = w8(bq + (nt * 16 + lm) * 64 + ks * 32 + lg * 8);
  }

  __syncthreads();   // K/V staged

  unsigned short* sQw = sQ[w];

  // interleaved chunk assignment: wave w takes chunks w, w+4, w+8, w+12 (32 rows each)
  for (int c = 0; c < 4; ++c) {
    const int chunk = c * 4 + w;
    const int qb = chunk * 32;

    // ---- Q projection for rows [qb, qb+32) -> sQ (swizzled) ----
#pragma unroll
    for (int mt = 0; mt < 2; ++mt) {
      int r0 = qb + mt * 16;
      short8 aX[2];
#pragma unroll
      for (int ks = 0; ks < 2; ++ks)
        aX[ks] = *(const short8*)(xn + (r0 + lm) * 64 + ks * 32 + lg * 8);
#pragma unroll
      for (int nt = 0; nt < 4; ++nt) {
        f32x4 acc = zero4;
        acc = MFMA16(aX[0], wqB[nt][0], acc);
        acc = MFMA16(aX[1], wqB[nt][1], acc);
#pragma unroll
        for (int r = 0; r < 4; ++r) {
          int qr = mt * 16 + lg * 4 + r;
          int e  = nt * 16 + lm;
          sQw[qr * 64 + (e ^ ((qr & 7) << 3))] = f2b(acc[r]);
        }
      }
    }
    // Q B-fragments: col = qrow local (lane%16), k = e
    short8 qB[2][2];
#pragma unroll
    for (int qn = 0; qn < 2; ++qn)
#pragma unroll
      for (int ks = 0; ks < 2; ++ks) {
        int qr = qn * 16 + lm;
        qB[qn][ks] = *(const short8*)&sQw[qr * 64 + ((ks * 32 + lg * 8) ^ ((qr & 7) << 3))];
      }

    f32x4 oAcc[2][4];
#pragma unroll
    for (int mo = 0; mo < 2; ++mo)
#pragma unroll
      for (int ot = 0; ot < 4; ++ot) oAcc[mo][ot] = zero4;
    float mrun[2] = {-1e30f, -1e30f};
    float lsum[2] = {0.f, 0.f};

    // ---- slab loop: 32 keys per iteration, only the kb==qb slab crosses the diagonal ----
    for (int kb = 0; kb <= qb; kb += 32) {
      const bool diag = (kb == qb);
      // K A-fragments (m = key row)
      short8 aK[2][2];
#pragma unroll
      for (int km = 0; km < 2; ++km)
#pragma unroll
        for (int ks = 0; ks < 2; ++ks) {
          int row = kb + km * 16 + lm;
          aK[km][ks] = *(const short8*)&sK[row * 64 + ((ks * 32 + lg * 8) ^ ((row & 7) << 3))];
        }
      // S^T = K . Q^T : C row = key (4*lg+r), C col = qrow (lm)
      f32x4 st[2][2];
#pragma unroll
      for (int km = 0; km < 2; ++km)
#pragma unroll
        for (int qn = 0; qn < 2; ++qn) {
          f32x4 acc = zero4;
          acc = MFMA16(aK[km][0], qB[qn][0], acc);
          acc = MFMA16(aK[km][1], qB[qn][1], acc);
          st[km][qn] = acc;
        }
      // online softmax (row = qrow lives in lane%16; reduce over regs then lanes 16,32)
      float corr[2];
#pragma unroll
      for (int qn = 0; qn < 2; ++qn) {
        int qrow = qb + qn * 16 + lm;
        float mx = -1e30f;
#pragma unroll
        for (int km = 0; km < 2; ++km)
#pragma unroll
          for (int r = 0; r < 4; ++r) {
            float v = st[km][qn][r] * 0.125f;     // 1/sqrt(64)
            if (diag) {
              int key = kb + km * 16 + lg * 4 + r;
              if (key > qrow) v = -1e30f;         // causal mask
            }
            st[km][qn][r] = v;
            mx = fmaxf(mx, v);
          }
        mx = fmaxf(mx, __shfl_xor(mx, 16));
        mx = fmaxf(mx, __shfl_xor(mx, 32));
        float mnew = fmaxf(mrun[qn], mx);
        float co = __expf(mrun[qn] - mnew);
        float rs = 0.f;
#pragma unroll
        for (int km = 0; km < 2; ++km)
#pragma unroll
          for (int r = 0; r < 4; ++r) {
            float e = __expf(st[km][qn][r] - mnew);
            st[km][qn][r] = e;
            rs += e;
          }
        rs += __shfl_xor(rs, 16);
        rs += __shfl_xor(rs, 32);
        lsum[qn] = lsum[qn] * co + rs;
        mrun[qn] = mnew;
        corr[qn] = co;
      }
      // V B-fragments: kappa2(g,i) = 4g + (i&3) + 16*(i>>2)  (matches P register layout)
      short8 vB[4];
#pragma unroll
      for (int ot = 0; ot < 4; ++ot) {
        int o = ot * 16 + lm;
        u16x4 lo = *(const u16x4*)&sVT[o * 512 + ((kb + lg * 4) ^ ((o & 7) << 3))];
        u16x4 hi = *(const u16x4*)&sVT[o * 512 + ((kb + 16 + lg * 4) ^ ((o & 7) << 3))];
        short8 v;
        v[0]=(short)lo[0]; v[1]=(short)lo[1]; v[2]=(short)lo[2]; v[3]=(short)lo[3];
        v[4]=(short)hi[0]; v[5]=(short)hi[1]; v[6]=(short)hi[2]; v[7]=(short)hi[3];
        vB[ot] = v;
      }
      // rescale O and accumulate P.V  (P packs straight from st registers)
#pragma unroll
      for (int mo = 0; mo < 2; ++mo) {
        float cr[4];
#pragma unroll
        for (int r = 0; r < 4; ++r) cr[r] = __shfl(corr[mo], lg * 4 + r);
        short8 pA;
#pragma unroll
        for (int i = 0; i < 8; ++i) pA[i] = (short)f2b(st[i >> 2][mo][i & 3]);
#pragma unroll
        for (int ot = 0; ot < 4; ++ot) {
          f32x4 oa = oAcc[mo][ot];
#pragma unroll
          for (int r = 0; r < 4; ++r) oa[r] *= cr[r];
          oAcc[mo][ot] = MFMA16(pA, vB[ot], oa);
        }
      }
    }

    // ---- normalize, transpose through sQ, coalesced store to heads[t][n][h*64+o] ----
#pragma unroll
    for (int mo = 0; mo < 2; ++mo) {
      float li[4];
#pragma unroll
      for (int r = 0; r < 4; ++r) li[r] = 1.0f / __shfl(lsum[mo], lg * 4 + r);
#pragma unroll
      for (int ot = 0; ot < 4; ++ot)
#pragma unroll
        for (int r = 0; r < 4; ++r) {
          int qr = mo * 16 + lg * 4 + r;
          int e  = ot * 16 + lm;
          sQw[qr * 64 + (e ^ ((qr & 7) << 3))] = f2b(oAcc[mo][ot][r] * li[r]);
        }
    }
#pragma unroll
    for (int j = 0; j < 8; ++j) {
      int tl = j * 4 + lg;
      int ob = lm * 4;
      u16x4 v = *(const u16x4*)&sQw[tl * 64 + (ob ^ ((tl & 7) << 3))];
      int t = qb + tl;
      *(u16x4*)&heads[(t * 128 + n) * 256 + h * 64 + ob] = v;
    }
  }
}

// ---------------- kernel 3: out = heads[65536,256] @ wo^T  (MFMA) ----------------
__global__ __launch_bounds__(256) void outproj_kernel(
    const unsigned short* __restrict__ heads,
    const float* __restrict__ wo,
    float* __restrict__ out) {
  const int w  = threadIdx.x >> 6;
  const int l  = threadIdx.x & 63;
  const int lg = l >> 4, lm = l & 15;
  const f32x4 zero4 = {0.f, 0.f, 0.f, 0.f};

  short8 woB[4][8];   // B[k=c][n=o'] = wo[o'][c]
#pragma unroll
  for (int nt = 0; nt < 4; ++nt)
#pragma unroll
    for (int ks = 0; ks < 8; ++ks)
      woB[nt][ks] = w8(wo + (nt * 16 + lm) * 256 + ks * 32 + lg * 8);

  const int wid = blockIdx.x * 4 + w;
  for (int it = 0; it < 2; ++it) {
    int r0 = (wid * 2 + it) * 16;
    f32x4 acc[4];
#pragma unroll
    for (int nt = 0; nt < 4; ++nt) acc[nt] = zero4;
#pragma unroll
    for (int ks = 0; ks < 8; ++ks) {
      short8 aF = *(const short8*)&heads[(r0 + lm) * 256 + ks * 32 + lg * 8];
#pragma unroll
      for (int nt = 0; nt < 4; ++nt)
        acc[nt] = MFMA16(aF, woB[nt][ks], acc[nt]);
    }
#pragma unroll
    for (int nt = 0; nt < 4; ++nt)
#pragma unroll
      for (int r = 0; r < 4; ++r)
        out[(r0 + lg * 4 + r) * 64 + nt * 16 + lm] = acc[nt][r];
  }
}

// ---------------- launch ----------------
extern "C" void kernel_launch(void* const* d_in, const int* in_sizes, int n_in,
                              void* d_out, int out_size, void* d_ws, size_t ws_size,
                              hipStream_t stream) {
  const float* x  = (const float*)d_in[0];
  const float* pe = (const float*)d_in[1];
  const float* wq = (const float*)d_in[2];
  const float* wk = (const float*)d_in[3];
  const float* wv = (const float*)d_in[4];
  const float* wo = (const float*)d_in[5];
  float* out = (float*)d_out;

  unsigned short* xinT  = (unsigned short*)d_ws;                          // 8.4 MB  [N][T][D] bf16
  unsigned short* heads = (unsigned short*)((char*)d_ws + (16u << 20));   // 33.5 MB [T*N][256] bf16

  prep_kernel<<<8192, 256, 0, stream>>>(x, pe, (unsigned*)xinT);
  attn_kernel<<<512, 256, 0, stream>>>(xinT, wq, wk, wv, heads);
  outproj_kernel<<<512, 256, 0, stream>>>(heads, wo, out);
}